// Round 3
// baseline (556.985 us; speedup 1.0000x reference)
//
#include <hip/hip_runtime.h>

#define NH 128

// ---------------------------------------------------------------------------
// 1) Exclusive prefix scan of grid_sizes -> c[0..G], c[G] = total
// ---------------------------------------------------------------------------
__global__ void scan_kernel(const int* __restrict__ gs, int* __restrict__ c, int G) {
    __shared__ int part[1024];
    int t = threadIdx.x;
    int chunk = (G + 1023) >> 10;
    int b = t * chunk;
    int e = min(b + chunk, G);
    int s = 0;
    for (int i = b; i < e; ++i) s += gs[i];
    part[t] = s;
    __syncthreads();
    for (int off = 1; off < 1024; off <<= 1) {
        int val = (t >= off) ? part[t - off] : 0;
        __syncthreads();
        part[t] += val;
        __syncthreads();
    }
    int excl = (t == 0) ? 0 : part[t - 1];
    for (int i = b; i < e; ++i) { c[i] = excl; excl += gs[i]; }
    if (t == 1023) c[G] = part[1023];
}

// ---------------------------------------------------------------------------
// 2a) A = Wk @ Wi,  u = Wk @ bi
// ---------------------------------------------------------------------------
__global__ void matA_kernel(const float* __restrict__ Wk, const float* __restrict__ Wi,
                            const float* __restrict__ bi,
                            float* __restrict__ A, float* __restrict__ u) {
    int tid = blockIdx.x * blockDim.x + threadIdx.x;  // 0..NH*NH-1
    int e = tid >> 7, d = tid & (NH - 1);
    float acc = 0.f;
    for (int f = 0; f < NH; ++f) acc += Wk[e * NH + f] * Wi[f * NH + d];
    A[e * NH + d] = acc;
    if (tid < NH) {
        float s = 0.f;
        for (int f = 0; f < NH; ++f) s += Wk[tid * NH + f] * bi[f];
        u[tid] = s;
    }
}

// ---------------------------------------------------------------------------
// 2b) Bt[f*NH+d] = sum_e Wi[e,d]*A[e,f];  v = Wi^T u;  w[f] = bi.A[:,f];
//     s0 = bi.u + bk
// ---------------------------------------------------------------------------
__global__ void matB_kernel(const float* __restrict__ Wi, const float* __restrict__ bi,
                            const float* __restrict__ bk,
                            const float* __restrict__ A, const float* __restrict__ u,
                            float* __restrict__ Bt, float* __restrict__ v,
                            float* __restrict__ w, float* __restrict__ s0) {
    int tid = blockIdx.x * blockDim.x + threadIdx.x;
    int i = tid & (NH - 1);
    int j = tid >> 7;
    float acc = 0.f;
    for (int e = 0; e < NH; ++e) acc += Wi[e * NH + i] * A[e * NH + j];
    Bt[j * NH + i] = acc;
    if (tid < NH) {
        float s = 0.f;
        for (int e = 0; e < NH; ++e) s += Wi[e * NH + tid] * u[e];
        v[tid] = s;
    } else if (tid < 2 * NH) {
        int jj = tid - NH;
        float s = 0.f;
        for (int e = 0; e < NH; ++e) s += bi[e] * A[e * NH + jj];
        w[jj] = s;
    }
    if (tid == 0) {
        float s = 0.f;
        for (int e = 0; e < NH; ++e) s += bi[e] * u[e];
        s0[0] = s + bk[0];
    }
}

// ---------------------------------------------------------------------------
// 3) Fused seg_mean + matvec: block per segment.
//    m = mean of gathered embedding_ rows; Q[g] = B m + v; C2[g] = w.m + s0
// ---------------------------------------------------------------------------
__global__ void seg_q_kernel(const float* __restrict__ emb_, const int* __restrict__ pos,
                             const int* __restrict__ c,
                             const float* __restrict__ Bt, const float* __restrict__ v,
                             const float* __restrict__ w, const float* __restrict__ s0,
                             float* __restrict__ Q, float* __restrict__ C2, int G) {
    __shared__ float smf[8 * NH];
    __shared__ float m[NH];
    __shared__ float half_acc[2][NH];
    __shared__ float red[2];
    int g = blockIdx.x;
    int t = threadIdx.x;            // 256
    int lane = t & 31, slot = t >> 5;
    int b = c[g], e = c[g + 1];

    float4 acc = make_float4(0.f, 0.f, 0.f, 0.f);
    for (int r = b + slot; r < e; r += 8) {
        int row = pos[r];
        const float4 a = ((const float4*)(emb_ + (size_t)row * NH))[lane];
        acc.x += a.x; acc.y += a.y; acc.z += a.z; acc.w += a.w;
    }
    ((float4*)(smf + slot * NH))[lane] = acc;
    __syncthreads();
    if (t < NH) {
        float s = 0.f;
#pragma unroll
        for (int i = 0; i < 8; ++i) s += smf[i * NH + t];
        m[t] = s / (float)max(e - b, 1);
    }
    __syncthreads();

    // matvec: threads 0-127 take f in [0,64), threads 128-255 take f in [64,128)
    int d = t & (NH - 1);
    int h = t >> 7;
    int f0 = h * 64;
    float acc2 = 0.f;
#pragma unroll
    for (int f = 0; f < 64; ++f)
        acc2 += Bt[(size_t)(f0 + f) * NH + d] * m[f0 + f];
    half_acc[h][d] = acc2;

    // C2 = w.m + s0 (2-wave shuffle reduce over t<128)
    if (t < NH) {
        float tv = w[t] * m[t];
#pragma unroll
        for (int off = 32; off; off >>= 1) tv += __shfl_xor(tv, off);
        if ((t & 63) == 0) red[t >> 6] = tv;
    }
    __syncthreads();
    if (t < NH)
        Q[(size_t)g * NH + t] = half_acc[0][t] + half_acc[1][t] + v[t];
    if (t == 0)
        C2[g] = red[0] + red[1] + s0[0];
}

// ---------------------------------------------------------------------------
// 4) logits: block per segment; 8 x 32-lane slots, 2 samples in flight per
//    slot iteration; LDS-staged indices and results; coalesced stores.
// ---------------------------------------------------------------------------
__global__ void logits_kernel(const float* __restrict__ emb, const int* __restrict__ pos,
                              const int* __restrict__ neg, const int* __restrict__ c,
                              const float* __restrict__ Q, const float* __restrict__ C2,
                              float* __restrict__ out, int P, int ratio) {
    __shared__ float qs[NH];
    __shared__ int idx[512];
    __shared__ float res[512];
    int g = blockIdx.x;
    int t = threadIdx.x;            // 256
    if (t < NH) qs[t] = Q[(size_t)g * NH + t];
    int pb = c[g], pe = c[g + 1];
    int np = pe - pb;
    int nb = pb * ratio;
    int tot = np + np * ratio;
    int lane = t & 31, slot = t >> 5;
    __syncthreads();
    float4 qr = ((const float4*)qs)[lane];
    float c2 = C2[g];

    for (int k0 = 0; k0 < tot; k0 += 512) {
        int kend = min(tot - k0, 512);
        for (int k = t; k < kend; k += 256) {
            int kk = k0 + k;
            idx[k] = (kk < np) ? pos[pb + kk] : neg[nb + kk - np];
        }
        __syncthreads();
        for (int k = slot; k < kend; k += 16) {
            int k1 = k + 8;
            int row0 = idx[k];
            const float4 a0 = ((const float4*)(emb + (size_t)row0 * NH))[lane];
            float4 a1;
            int row1 = -1;
            if (k1 < kend) {
                row1 = idx[k1];
                a1 = ((const float4*)(emb + (size_t)row1 * NH))[lane];
            }
            float v0 = a0.x * qr.x + a0.y * qr.y + a0.z * qr.z + a0.w * qr.w;
#pragma unroll
            for (int off = 16; off; off >>= 1) v0 += __shfl_xor(v0, off, 32);
            if (lane == 0) res[k] = v0 + c2;
            if (row1 >= 0) {
                float v1 = a1.x * qr.x + a1.y * qr.y + a1.z * qr.z + a1.w * qr.w;
#pragma unroll
                for (int off = 16; off; off >>= 1) v1 += __shfl_xor(v1, off, 32);
                if (lane == 0) res[k1] = v1 + c2;
            }
        }
        __syncthreads();
        for (int k = t; k < kend; k += 256) {
            int kk = k0 + k;
            int o = (kk < np) ? (pb + kk) : (P + nb + kk - np);
            out[o] = res[k];
        }
        __syncthreads();
    }
}

// ---------------------------------------------------------------------------
extern "C" void kernel_launch(void* const* d_in, const int* in_sizes, int n_in,
                              void* d_out, int out_size, void* d_ws, size_t ws_size,
                              hipStream_t stream) {
    const float* embedding  = (const float*)d_in[0];
    const float* embedding_ = (const float*)d_in[1];
    const int*   grid_sizes = (const int*)d_in[2];
    const int*   pos        = (const int*)d_in[3];
    const int*   neg        = (const int*)d_in[4];
    const float* Wi         = (const float*)d_in[5];
    const float* bi         = (const float*)d_in[6];
    const float* Wk         = (const float*)d_in[7];
    const float* bk         = (const float*)d_in[8];

    int G = in_sizes[2];
    int P = in_sizes[3];
    int PN = in_sizes[4];
    int ratio = PN / P;

    char* ws = (char*)d_ws;
    size_t off = 0;
    auto alloc = [&](size_t bytes) {
        void* p = ws + off;
        off += (bytes + 255) & ~(size_t)255;
        return p;
    };
    int*   c   = (int*)  alloc((size_t)(G + 1) * sizeof(int));
    float* A   = (float*)alloc(NH * NH * sizeof(float));
    float* u   = (float*)alloc(NH * sizeof(float));
    float* Bt  = (float*)alloc(NH * NH * sizeof(float));
    float* v   = (float*)alloc(NH * sizeof(float));
    float* w   = (float*)alloc(NH * sizeof(float));
    float* s0  = (float*)alloc(sizeof(float));
    float* Q   = (float*)alloc((size_t)G * NH * sizeof(float));
    float* C2  = (float*)alloc((size_t)G * sizeof(float));
    (void)ws_size; (void)n_in; (void)out_size;

    hipLaunchKernelGGL(scan_kernel, dim3(1), dim3(1024), 0, stream, grid_sizes, c, G);
    hipLaunchKernelGGL(matA_kernel, dim3((NH * NH) / 256), dim3(256), 0, stream,
                       Wk, Wi, bi, A, u);
    hipLaunchKernelGGL(matB_kernel, dim3((NH * NH) / 256), dim3(256), 0, stream,
                       Wi, bi, bk, A, u, Bt, v, w, s0);
    hipLaunchKernelGGL(seg_q_kernel, dim3(G), dim3(256), 0, stream,
                       embedding_, pos, c, Bt, v, w, s0, Q, C2, G);
    hipLaunchKernelGGL(logits_kernel, dim3(G), dim3(256), 0, stream,
                       embedding, pos, neg, c, Q, C2, (float*)d_out, P, ratio);
}